// Round 13
// baseline (166.215 us; speedup 1.0000x reference)
//
#include <hip/hip_runtime.h>
#include <cstddef>
#include <cstdint>

#define N_    4096
#define C_    512
#define OUT_  256
#define EPSF  1e-5f

#define NCHK   8              // global top-8 candidates, fp64 re-checked
#define MAXN   8              // max stored neighbors
#define NT_    (N_/128)       // 32 stripes; triangle blocks = 528

#define XF4   (N_*C_/4)          // 524288
#define WF4   (C_*C_/4)          // 65536
#define FF4   (OUT_*C_/4)        // 32768
#define TOTF4 (XF4 + 2*WF4 + FF4)

#define NSYRK  (NT_*(NT_+1)/2)   // 528 syrk tiles
#define NUV    (32*16)           // 512 uv-gemm tiles (128x64)

#define HSTR  516                // padded h row stride in LDS (bank-spread)

typedef __attribute__((ext_vector_type(8))) short short8;
typedef __attribute__((ext_vector_type(4))) float f32x4;

typedef unsigned int u32;
typedef const u32 __attribute__((address_space(1)))* gptr_t;
typedef u32 __attribute__((address_space(3)))* lptr_t;

// Async global->LDS DMA, 16 B/lane. LDS dst = wave-uniform base + lane*16.
__device__ __forceinline__ void dma16(const unsigned short* g, unsigned short* l) {
    __builtin_amdgcn_global_load_lds((gptr_t)(uintptr_t)g, (lptr_t)(uintptr_t)l, 16, 0, 0);
}

__device__ __forceinline__ unsigned short f2bf(float f) {
    union { float f; unsigned u; } v; v.f = f;
    return (unsigned short)((v.u + 0x7FFFu + ((v.u >> 16) & 1u)) >> 16);
}
__device__ __forceinline__ float bf2f(unsigned short h) {
    union { unsigned u; float f; } v; v.u = ((unsigned)h) << 16;
    return v.f;
}

// bf16 (as u16) -> order-preserving u16 key (larger key == larger float)
__device__ __forceinline__ u32 bfkey(unsigned short u) {
    return (u & 0x8000u) ? (u ^ 0xFFFFu) : (u | 0x8000u);
}

// Packed-key top-8 insert (descending), single-u32 compares, constant idx.
__device__ __forceinline__ void key8_insert(u32* s, u32 key) {
    if (key <= s[7]) return;
    bool g0 = key > s[0], g1 = key > s[1], g2 = key > s[2], g3 = key > s[3],
         g4 = key > s[4], g5 = key > s[5], g6 = key > s[6];
    s[7] = g6 ? s[6] : key;
    s[6] = g5 ? s[5] : (g6 ? key : s[6]);
    s[5] = g4 ? s[4] : (g5 ? key : s[5]);
    s[4] = g3 ? s[3] : (g4 ? key : s[4]);
    s[3] = g2 ? s[2] : (g3 ? key : s[3]);
    s[2] = g1 ? s[1] : (g2 ? key : s[2]);
    s[1] = g0 ? s[0] : (g1 ? key : s[1]);
    s[0] = g0 ? key : s[0];
}

// ---------------------------------------------------------------------------
// Fused split: x -> xh (hi only), U/V -> wh/wl, fc -> fh/fl.
// ---------------------------------------------------------------------------
__global__ __launch_bounds__(256) void split_all(
    const float* __restrict__ x, const float* __restrict__ Uw,
    const float* __restrict__ Vw, const float* __restrict__ fcw,
    unsigned short* __restrict__ xh,
    unsigned short* __restrict__ wh, unsigned short* __restrict__ wl,
    unsigned short* __restrict__ fh, unsigned short* __restrict__ fl)
{
    int i = blockIdx.x * 256 + threadIdx.x;
    const float* src; unsigned short *hi, *lo; int j; bool wantLo = true;
    if (i < XF4)              { src = x;   hi = xh; lo = nullptr; wantLo = false; j = i; }
    else if (i < XF4 + WF4)   { src = Uw;  hi = wh; lo = wl; j = i - XF4; }
    else if (i < XF4 + 2*WF4) { src = Vw;  hi = wh + (size_t)C_*C_; lo = wl + (size_t)C_*C_; j = i - XF4 - WF4; }
    else                      { src = fcw; hi = fh; lo = fl; j = i - XF4 - 2*WF4; }
    float4 f = ((const float4*)src)[j];
    ushort4 h;
    h.x = f2bf(f.x); h.y = f2bf(f.y); h.z = f2bf(f.z); h.w = f2bf(f.w);
    ((ushort4*)hi)[j] = h;
    if (wantLo) {
        ushort4 l;
        l.x = f2bf(f.x - bf2f(h.x));
        l.y = f2bf(f.y - bf2f(h.y));
        l.z = f2bf(f.z - bf2f(h.z));
        l.w = f2bf(f.w - bf2f(h.w));
        ((ushort4*)lo)[j] = l;
    }
}

// ---------------------------------------------------------------------------
// Fused independent-work dispatch, 32 KB LDS. Blocks [0,528) = triangle syrk
// tiles (mirrored si write, stored as SORTABLE u16 KEYS); blocks [528,1040) =
// u|v GEMM 128x64 tiles, A = xh only. u -> zu fp32; v -> vb bf16.
// ---------------------------------------------------------------------------
union FusedSmem {
    struct { unsigned short A[128 * 64]; unsigned short B[128 * 64]; } stg;      // 32 KB
    unsigned short stile[128 * 66];                                               // 16.9 KB (half-tile)
    struct { unsigned short Ah[128*64]; unsigned short Bh[64*64]; unsigned short Bl[64*64]; } gm; // 32 KB
};

__global__ __launch_bounds__(256) void simuv(
    const unsigned short* __restrict__ xb, unsigned short* __restrict__ si,
    const unsigned short* __restrict__ xh,
    const unsigned short* __restrict__ wh, const unsigned short* __restrict__ wl,
    const float* __restrict__ Ub, const float* __restrict__ Vb,
    float* __restrict__ zu, unsigned short* __restrict__ vb)
{
    __shared__ FusedSmem sm;
    const int t = threadIdx.x;
    const int lane = t & 63, w = t >> 6;
    const int wr = w >> 1, wc = w & 1;
    const int col16 = lane & 15, quad = lane >> 4;
    const int ln8 = lane >> 3;
    const int csw = ((lane & 7) ^ ln8) * 8;   // XOR-swizzled chunk (bank spread)

    if (blockIdx.x < NSYRK) {
        // ================= triangle syrk tile =================
        int bi = 0, rem = blockIdx.x;
        while (rem >= NT_ - bi) { rem -= NT_ - bi; bi++; }
        const int bj = bi + rem;
        const int rowStart = bi * 128, colStart = bj * 128;

        f32x4 acc[4][4] = {};
        for (int k0 = 0; k0 < C_; k0 += 64) {
#pragma unroll
            for (int i = 0; i < 4; i++) {
                const int r8 = w * 32 + i * 8;
                dma16(xb + (size_t)(rowStart + r8 + ln8) * C_ + k0 + csw, &sm.stg.A[r8 * 64]);
                dma16(xb + (size_t)(colStart + r8 + ln8) * C_ + k0 + csw, &sm.stg.B[r8 * 64]);
            }
            __syncthreads();
#pragma unroll
            for (int ks = 0; ks < 2; ks++) {
                short8 af[4], bfr[4];
#pragma unroll
                for (int mt = 0; mt < 4; mt++) {
                    const int r = wr*64 + mt*16 + col16;
                    af[mt] = *(const short8*)&sm.stg.A[r * 64 + (((ks*4 + quad) ^ (r & 7)) * 8)];
                }
#pragma unroll
                for (int nt = 0; nt < 4; nt++) {
                    const int r = wc*64 + nt*16 + col16;
                    bfr[nt] = *(const short8*)&sm.stg.B[r * 64 + (((ks*4 + quad) ^ (r & 7)) * 8)];
                }
#pragma unroll
                for (int mt = 0; mt < 4; mt++)
#pragma unroll
                    for (int nt = 0; nt < 4; nt++)
                        acc[mt][nt] = __builtin_amdgcn_mfma_f32_16x16x32_bf16(
                            af[mt], bfr[nt], acc[mt][nt], 0, 0, 0);
            }
            __syncthreads();
        }

        // ---- epilogue: two 128x64 half-tiles, values stored as u16 KEYS ----
        for (int p = 0; p < 2; p++) {
            if (wc == p) {
#pragma unroll
                for (int mt = 0; mt < 4; mt++)
#pragma unroll
                    for (int nt = 0; nt < 4; nt++)
#pragma unroll
                        for (int r = 0; r < 4; r++)
                            sm.stile[(wr*64 + mt*16 + quad*4 + r) * 66 + nt*16 + col16] =
                                (unsigned short)bfkey(f2bf(acc[mt][nt][r]));
            }
            __syncthreads();
            {
                const int rr = t >> 1, seg = t & 1;
#pragma unroll
                for (int k = 0; k < 4; k++) {
                    short8 pk = *(const short8*)&sm.stile[rr * 66 + seg*32 + k*8];
                    *(short8*)&si[(size_t)(rowStart + rr) * N_ + colStart + p*64 + seg*32 + k*8] = pk;
                }
            }
            if (bi != bj) {
                const int cc = t >> 2, h2 = t & 3;
#pragma unroll
                for (int k = 0; k < 4; k++) {
                    short8 pk;
#pragma unroll
                    for (int e = 0; e < 8; e++)
                        pk[e] = (short)sm.stile[(h2*32 + k*8 + e) * 66 + cc];
                    *(short8*)&si[(size_t)(colStart + p*64 + cc) * N_ + rowStart + h2*32 + k*8] = pk;
                }
            }
            __syncthreads();
        }
    } else {
        // ========== u|v GEMM 128x64 tile, A = xh only (2-term split) ==========
        const int gb = blockIdx.x - NSYRK;          // 0..511
        const int rowStart = (gb >> 4) * 128;       // 32 row-tiles
        const int colStart = (gb & 15) * 64;        // 16 col-tiles (0..1023)

        f32x4 acc[4][2] = {};
        for (int k0 = 0; k0 < C_; k0 += 64) {
#pragma unroll
            for (int j = 0; j < 8; j++) {
                const int u = w * 8 + j;
                const unsigned short* gs; unsigned short* ld;
                if (u < 16)      { const int rb = u*8;       gs = xh + (size_t)(rowStart + rb + ln8) * C_; ld = sm.gm.Ah + rb*64; }
                else if (u < 24) { const int rb = (u-16)*8;  gs = wh + (size_t)(colStart + rb + ln8) * C_; ld = sm.gm.Bh + rb*64; }
                else             { const int rb = (u-24)*8;  gs = wl + (size_t)(colStart + rb + ln8) * C_; ld = sm.gm.Bl + rb*64; }
                dma16(gs + k0 + csw, ld);
            }
            __syncthreads();

#pragma unroll
            for (int ks = 0; ks < 2; ks++) {
                short8 bh2[2], bl2[2];
#pragma unroll
                for (int nt = 0; nt < 2; nt++) {
                    const int r = wc*32 + nt*16 + col16;
                    const int ro = r * 64 + (((ks*4 + quad) ^ (r & 7)) * 8);
                    bh2[nt] = *(const short8*)&sm.gm.Bh[ro];
                    bl2[nt] = *(const short8*)&sm.gm.Bl[ro];
                }
#pragma unroll
                for (int mt = 0; mt < 4; mt++) {
                    const int r = wr*64 + mt*16 + col16;
                    const int ro = r * 64 + (((ks*4 + quad) ^ (r & 7)) * 8);
                    short8 ah = *(const short8*)&sm.gm.Ah[ro];
#pragma unroll
                    for (int nt = 0; nt < 2; nt++) {
                        acc[mt][nt] = __builtin_amdgcn_mfma_f32_16x16x32_bf16(ah, bl2[nt], acc[mt][nt], 0, 0, 0);
                        acc[mt][nt] = __builtin_amdgcn_mfma_f32_16x16x32_bf16(ah, bh2[nt], acc[mt][nt], 0, 0, 0);
                    }
                }
            }
            __syncthreads();
        }

        if (colStart < 512) {   // u-part -> fp32 zu[N][512]
#pragma unroll
            for (int nt = 0; nt < 2; nt++) {
                const int col = colStart + wc*32 + nt*16 + col16;
                const float bns = Ub[col];
#pragma unroll
                for (int mt = 0; mt < 4; mt++)
#pragma unroll
                    for (int r = 0; r < 4; r++) {
                        const int row = rowStart + wr*64 + mt*16 + quad*4 + r;
                        zu[(size_t)row * 512 + col] = acc[mt][nt][r] + bns;
                    }
            }
        } else {                // v-part -> bf16 vb[N][512] (aggregate-only)
#pragma unroll
            for (int nt = 0; nt < 2; nt++) {
                const int col = colStart - 512 + wc*32 + nt*16 + col16;
                const float bns = Vb[col];
#pragma unroll
                for (int mt = 0; mt < 4; mt++)
#pragma unroll
                    for (int r = 0; r < 4; r++) {
                        const int row = rowStart + wr*64 + mt*16 + quad*4 + r;
                        vb[(size_t)row * 512 + col] = f2bf(acc[mt][nt][r] + bns);
                    }
            }
        }
    }
}

// ---------------------------------------------------------------------------
// Row selection + exact re-check, one wave per row (4 rows/block). si holds
// pre-transformed sortable keys; pack key<<16 | idx and compare as u32.
// ---------------------------------------------------------------------------
__global__ __launch_bounds__(256) void rowsel(
    const unsigned short* __restrict__ si, const float* __restrict__ x,
    int* __restrict__ nbr_idx, int* __restrict__ nbr_cnt,
    float* __restrict__ dinv_arr)
{
    const int wv = threadIdx.x >> 6, lane = threadIdx.x & 63;
    const int row = blockIdx.x * 4 + wv;

    u32 s[8] = {0, 0, 0, 0, 0, 0, 0, 0};
    const unsigned short* sr = si + (size_t)row * N_;
#pragma unroll
    for (int it = 0; it < 8; it++) {
        short8 pack = *(const short8*)&sr[it * 512 + lane * 8];
#pragma unroll
        for (int e = 0; e < 8; e++) {
            u32 key = ((u32)(unsigned short)pack[e] << 16) | (u32)(it * 512 + lane * 8 + e);
            key8_insert(s, key);
        }
    }
#pragma unroll
    for (int off = 1; off < 64; off <<= 1) {
        u32 o[8];
#pragma unroll
        for (int m = 0; m < 8; m++) o[m] = __shfl_xor(s[m], off);
#pragma unroll
        for (int m = 0; m < 8; m++) key8_insert(s, o[m]);
    }
    int tj[NCHK];
#pragma unroll
    for (int c = 0; c < NCHK; c++) tj[c] = (int)(s[c] & 0xFFFu);   // all lanes agree

    const float* xr = x + (size_t)row * C_;
    float xrv[8];
#pragma unroll
    for (int k = 0; k < 8; k++) xrv[k] = xr[lane + k*64];
    double dvr[NCHK];
#pragma unroll
    for (int c = 0; c < NCHK; c++) {
        const float* xj = x + (size_t)tj[c] * C_;
        double sum = 0.0;
#pragma unroll
        for (int k = 0; k < 8; k++)
            sum += (double)xrv[k] * (double)xj[lane + k*64];
#pragma unroll
        for (int off = 32; off; off >>= 1) sum += __shfl_xor(sum, off);
        dvr[c] = sum;
    }
    double m0 = -1e300, m1 = -1e300, m2 = -1e300, m3 = -1e300;
#pragma unroll
    for (int c = 0; c < NCHK; c++) {
        double v = dvr[c];
        if (v > m3) {
            if (v > m0)      { m3 = m2; m2 = m1; m1 = m0; m0 = v; }
            else if (v > m1) { m3 = m2; m2 = m1; m1 = v; }
            else if (v > m2) { m3 = m2; m2 = v; }
            else               m3 = v;
        }
    }
    const double thr = m3;
    if (lane == 0) {
        int cnt = 0;
#pragma unroll
        for (int c = 0; c < NCHK; c++) {
            bool keep = dvr[c] >= thr;
            if (keep) nbr_idx[(size_t)row * MAXN + cnt] = tj[c];
            cnt += keep ? 1 : 0;
        }
        nbr_cnt[row]  = cnt;
        dinv_arr[row] = (float)(1.0 / sqrt((double)cnt));
    }
}

// ---------------------------------------------------------------------------
// Fused aggregate+BN+relu + fc GEMM. 256 blocks x 16 rows.
// Phase 1: wave w aggregates rows w*4..w*4+3 (verbatim R12 math), h -> LDS
// (hi/lo planes, padded stride). Phase 2: 16x256 out tile; A-frags from LDS,
// B-frags (fh/fl, L2-hot 256 KB) straight from global; 3-term split MFMA.
// ---------------------------------------------------------------------------
__global__ __launch_bounds__(256) void agg_fc(
    const float* __restrict__ x, const float* __restrict__ zu,
    const unsigned short* __restrict__ vb,
    const int* __restrict__ nbr_idx, const int* __restrict__ nbr_cnt,
    const float* __restrict__ dinv_arr,
    const unsigned short* __restrict__ fh, const unsigned short* __restrict__ fl,
    const float* __restrict__ fcb, float* __restrict__ out)
{
    __shared__ unsigned short hhp[16 * HSTR];   // h hi plane
    __shared__ unsigned short hlp[16 * HSTR];   // h lo plane
    const int t = threadIdx.x;
    const int lane = t & 63, w = t >> 6;
    const int col16 = lane & 15, quad = lane >> 4;
    const int rowBase = blockIdx.x * 16;

    // ---------------- phase 1: aggregate + BN, 4 rows per wave ----------------
    for (int rr = 0; rr < 4; rr++) {
        const int lrow = w * 4 + rr;
        const int row = rowBase + lrow;
        const int cnt = nbr_cnt[row];
        const float di = dinv_arr[row];
        const int c0 = lane * 8;

        const float* zr = zu + (size_t)row * 512 + c0;
        float4 z0 = *(const float4*)zr;
        float4 z1 = *(const float4*)(zr + 4);
#pragma unroll
        for (int m = 0; m < MAXN; m++) {
            if (m < cnt) {
                const int j = nbr_idx[(size_t)row * MAXN + m];
                const float wgt = di * dinv_arr[j];
                short8 vv = *(const short8*)&vb[(size_t)j * 512 + c0];
                z0.x += wgt * bf2f((unsigned short)vv[0]);
                z0.y += wgt * bf2f((unsigned short)vv[1]);
                z0.z += wgt * bf2f((unsigned short)vv[2]);
                z0.w += wgt * bf2f((unsigned short)vv[3]);
                z1.x += wgt * bf2f((unsigned short)vv[4]);
                z1.y += wgt * bf2f((unsigned short)vv[5]);
                z1.z += wgt * bf2f((unsigned short)vv[6]);
                z1.w += wgt * bf2f((unsigned short)vv[7]);
            }
        }
        float sum  = z0.x + z0.y + z0.z + z0.w + z1.x + z1.y + z1.z + z1.w;
        float sumq = z0.x*z0.x + z0.y*z0.y + z0.z*z0.z + z0.w*z0.w
                   + z1.x*z1.x + z1.y*z1.y + z1.z*z1.z + z1.w*z1.w;
#pragma unroll
        for (int off = 32; off; off >>= 1) {
            sum  += __shfl_xor(sum, off);
            sumq += __shfl_xor(sumq, off);
        }
        const float mean = sum / (float)C_;
        const float var  = sumq / (float)C_ - mean * mean;
        const float istd = 1.0f / sqrtf(var + EPSF);

        const float* xr = x + (size_t)row * C_ + c0;
        float4 x0 = *(const float4*)xr;
        float4 x1 = *(const float4*)(xr + 4);
        float hv[8];
        hv[0] = fmaxf(x0.x + (z0.x - mean) * istd, 0.f);
        hv[1] = fmaxf(x0.y + (z0.y - mean) * istd, 0.f);
        hv[2] = fmaxf(x0.z + (z0.z - mean) * istd, 0.f);
        hv[3] = fmaxf(x0.w + (z0.w - mean) * istd, 0.f);
        hv[4] = fmaxf(x1.x + (z1.x - mean) * istd, 0.f);
        hv[5] = fmaxf(x1.y + (z1.y - mean) * istd, 0.f);
        hv[6] = fmaxf(x1.z + (z1.z - mean) * istd, 0.f);
        hv[7] = fmaxf(x1.w + (z1.w - mean) * istd, 0.f);
        short8 hb, lb;
#pragma unroll
        for (int e = 0; e < 8; e++) {
            unsigned short b = f2bf(hv[e]);
            hb[e] = (short)b;
            lb[e] = (short)f2bf(hv[e] - bf2f(b));
        }
        *(short8*)&hhp[lrow * HSTR + c0] = hb;
        *(short8*)&hlp[lrow * HSTR + c0] = lb;
    }
    __syncthreads();

    // ---------------- phase 2: out[16 rows][256 cols], wave w -> cols w*64 ----
    const int colBase = w * 64;
    f32x4 acc[4] = {};
    for (int kst = 0; kst < 16; kst++) {
        const int ko = kst * 32 + quad * 8;
        short8 ah = *(const short8*)&hhp[col16 * HSTR + ko];
        short8 al = *(const short8*)&hlp[col16 * HSTR + ko];
#pragma unroll
        for (int nt = 0; nt < 4; nt++) {
            const int bRow = colBase + nt * 16 + col16;
            short8 bh = *(const short8*)&fh[(size_t)bRow * C_ + ko];
            short8 bl = *(const short8*)&fl[(size_t)bRow * C_ + ko];
            acc[nt] = __builtin_amdgcn_mfma_f32_16x16x32_bf16(al, bh, acc[nt], 0, 0, 0);
            acc[nt] = __builtin_amdgcn_mfma_f32_16x16x32_bf16(ah, bl, acc[nt], 0, 0, 0);
            acc[nt] = __builtin_amdgcn_mfma_f32_16x16x32_bf16(ah, bh, acc[nt], 0, 0, 0);
        }
    }
#pragma unroll
    for (int nt = 0; nt < 4; nt++) {
        const int col = colBase + nt * 16 + col16;
        const float bns = fcb[col];
#pragma unroll
        for (int r = 0; r < 4; r++) {
            const int row = rowBase + quad * 4 + r;
            out[(size_t)row * OUT_ + col] = acc[nt][r] + bns;
        }
    }
}

// ---------------------------------------------------------------------------
extern "C" void kernel_launch(void* const* d_in, const int* in_sizes, int n_in,
                              void* d_out, int out_size, void* d_ws, size_t ws_size,
                              hipStream_t stream)
{
    const float* x    = (const float*)d_in[0];
    const float* U_w  = (const float*)d_in[1];
    const float* U_b  = (const float*)d_in[2];
    const float* V_w  = (const float*)d_in[3];
    const float* V_b  = (const float*)d_in[4];
    const float* fc_w = (const float*)d_in[5];
    const float* fc_b = (const float*)d_in[6];
    float* out = (float*)d_out;

    char* p = (char*)d_ws;
    auto alloc = [&](size_t bytes) { char* r = p; p += (bytes + 255) & ~(size_t)255; return r; };
    unsigned short* si = (unsigned short*)alloc((size_t)N_ * N_ * 2);     // 32 MB (keys)
    unsigned short* xh = (unsigned short*)alloc((size_t)N_ * C_ * 2);
    unsigned short* wh = (unsigned short*)alloc((size_t)1024 * C_ * 2);   // [U_w; V_w] hi
    unsigned short* wl = (unsigned short*)alloc((size_t)1024 * C_ * 2);   // [U_w; V_w] lo
    unsigned short* fh = (unsigned short*)alloc((size_t)OUT_ * C_ * 2);
    unsigned short* fl = (unsigned short*)alloc((size_t)OUT_ * C_ * 2);
    float*          zu = (float*)alloc((size_t)N_ * 512 * 4);             // u fp32
    unsigned short* vb = (unsigned short*)alloc((size_t)N_ * 512 * 2);    // v bf16
    int*   nbr_idx  = (int*)  alloc((size_t)N_ * MAXN * 4);
    int*   nbr_cnt  = (int*)  alloc((size_t)N_ * 4);
    float* dinv     = (float*)alloc((size_t)N_ * 4);

    // 1. fp32 -> bf16 planes (x hi-only; U/V and fc hi+lo)
    hipLaunchKernelGGL(split_all, dim3(TOTF4 / 256), dim3(256), 0, stream,
                       x, U_w, V_w, fc_w, xh, wh, wl, fh, fl);

    // 2. fused: triangle similarity (key-encoded, mirrored) + [u|v] GEMM
    hipLaunchKernelGGL(simuv, dim3(NSYRK + NUV), dim3(256), 0, stream,
                       xh, si, xh, wh, wl, U_b, V_b, zu, vb);

    // 3. per-row packed-key top-8 + fp64 re-check -> neighbors, deg, dinv
    hipLaunchKernelGGL(rowsel, dim3(N_/4), dim3(256), 0, stream,
                       si, x, nbr_idx, nbr_cnt, dinv);

    // 4. fused aggregate + BN + relu + fc GEMM -> out
    hipLaunchKernelGGL(agg_fc, dim3(N_/16), dim3(256), 0, stream,
                       x, zu, vb, nbr_idx, nbr_cnt, dinv, fh, fl, fc_b, out);
}

// Round 14
// 154.749 us; speedup vs baseline: 1.0741x; 1.0741x over previous
//
#include <hip/hip_runtime.h>
#include <cstddef>
#include <cstdint>

#define N_    4096
#define C_    512
#define OUT_  256
#define EPSF  1e-5f

#define NCHK   8              // global top-8 candidates, fp64 re-checked
#define MAXN   8              // max stored neighbors
#define NT_    (N_/128)       // 32 stripes; triangle blocks = 528

#define XF4   (N_*C_/4)          // 524288
#define WF4   (C_*C_/4)          // 65536
#define FF4   (OUT_*C_/4)        // 32768
#define TOTF4 (XF4 + 2*WF4 + FF4)

#define NSYRK  (NT_*(NT_+1)/2)   // 528 syrk tiles
#define NUV    (32*16)           // 512 uv-gemm tiles (128x64)

typedef __attribute__((ext_vector_type(8))) short short8;
typedef __attribute__((ext_vector_type(4))) float f32x4;

typedef unsigned int u32;
typedef const u32 __attribute__((address_space(1)))* gptr_t;
typedef u32 __attribute__((address_space(3)))* lptr_t;

// Async global->LDS DMA, 16 B/lane. LDS dst = wave-uniform base + lane*16.
__device__ __forceinline__ void dma16(const unsigned short* g, unsigned short* l) {
    __builtin_amdgcn_global_load_lds((gptr_t)(uintptr_t)g, (lptr_t)(uintptr_t)l, 16, 0, 0);
}

__device__ __forceinline__ unsigned short f2bf(float f) {
    union { float f; unsigned u; } v; v.f = f;
    return (unsigned short)((v.u + 0x7FFFu + ((v.u >> 16) & 1u)) >> 16);
}
__device__ __forceinline__ float bf2f(unsigned short h) {
    union { unsigned u; float f; } v; v.u = ((unsigned)h) << 16;
    return v.f;
}

// bf16 (as u16) -> order-preserving u16 key (larger key == larger float)
__device__ __forceinline__ u32 bfkey(unsigned short u) {
    return (u & 0x8000u) ? (u ^ 0xFFFFu) : (u | 0x8000u);
}

// Packed-key top-8 insert (descending), single-u32 compares, constant idx.
__device__ __forceinline__ void key8_insert(u32* s, u32 key) {
    if (key <= s[7]) return;
    bool g0 = key > s[0], g1 = key > s[1], g2 = key > s[2], g3 = key > s[3],
         g4 = key > s[4], g5 = key > s[5], g6 = key > s[6];
    s[7] = g6 ? s[6] : key;
    s[6] = g5 ? s[5] : (g6 ? key : s[6]);
    s[5] = g4 ? s[4] : (g5 ? key : s[5]);
    s[4] = g3 ? s[3] : (g4 ? key : s[4]);
    s[3] = g2 ? s[2] : (g3 ? key : s[3]);
    s[2] = g1 ? s[1] : (g2 ? key : s[2]);
    s[1] = g0 ? s[0] : (g1 ? key : s[1]);
    s[0] = g0 ? key : s[0];
}

// ---------------------------------------------------------------------------
// Fused split: x -> xh (hi only), U/V -> wh/wl, fc -> fh/fl.
// ---------------------------------------------------------------------------
__global__ __launch_bounds__(256) void split_all(
    const float* __restrict__ x, const float* __restrict__ Uw,
    const float* __restrict__ Vw, const float* __restrict__ fcw,
    unsigned short* __restrict__ xh,
    unsigned short* __restrict__ wh, unsigned short* __restrict__ wl,
    unsigned short* __restrict__ fh, unsigned short* __restrict__ fl)
{
    int i = blockIdx.x * 256 + threadIdx.x;
    const float* src; unsigned short *hi, *lo; int j; bool wantLo = true;
    if (i < XF4)              { src = x;   hi = xh; lo = nullptr; wantLo = false; j = i; }
    else if (i < XF4 + WF4)   { src = Uw;  hi = wh; lo = wl; j = i - XF4; }
    else if (i < XF4 + 2*WF4) { src = Vw;  hi = wh + (size_t)C_*C_; lo = wl + (size_t)C_*C_; j = i - XF4 - WF4; }
    else                      { src = fcw; hi = fh; lo = fl; j = i - XF4 - 2*WF4; }
    float4 f = ((const float4*)src)[j];
    ushort4 h;
    h.x = f2bf(f.x); h.y = f2bf(f.y); h.z = f2bf(f.z); h.w = f2bf(f.w);
    ((ushort4*)hi)[j] = h;
    if (wantLo) {
        ushort4 l;
        l.x = f2bf(f.x - bf2f(h.x));
        l.y = f2bf(f.y - bf2f(h.y));
        l.z = f2bf(f.z - bf2f(h.z));
        l.w = f2bf(f.w - bf2f(h.w));
        ((ushort4*)lo)[j] = l;
    }
}

// ---------------------------------------------------------------------------
// Fused independent-work dispatch, 32 KB LDS. Blocks [0,528) = triangle syrk
// tiles (mirrored si write, stored as SORTABLE u16 KEYS); blocks [528,1040) =
// u|v GEMM 128x64 tiles, A = xh only. u -> zu fp32; v -> vb bf16.
// ---------------------------------------------------------------------------
union FusedSmem {
    struct { unsigned short A[128 * 64]; unsigned short B[128 * 64]; } stg;      // 32 KB
    unsigned short stile[128 * 66];                                               // 16.9 KB (half-tile)
    struct { unsigned short Ah[128*64]; unsigned short Bh[64*64]; unsigned short Bl[64*64]; } gm; // 32 KB
};

__global__ __launch_bounds__(256) void simuv(
    const unsigned short* __restrict__ xb, unsigned short* __restrict__ si,
    const unsigned short* __restrict__ xh,
    const unsigned short* __restrict__ wh, const unsigned short* __restrict__ wl,
    const float* __restrict__ Ub, const float* __restrict__ Vb,
    float* __restrict__ zu, unsigned short* __restrict__ vb)
{
    __shared__ FusedSmem sm;
    const int t = threadIdx.x;
    const int lane = t & 63, w = t >> 6;
    const int wr = w >> 1, wc = w & 1;
    const int col16 = lane & 15, quad = lane >> 4;
    const int ln8 = lane >> 3;
    const int csw = ((lane & 7) ^ ln8) * 8;   // XOR-swizzled chunk (bank spread)

    if (blockIdx.x < NSYRK) {
        // ================= triangle syrk tile =================
        int bi = 0, rem = blockIdx.x;
        while (rem >= NT_ - bi) { rem -= NT_ - bi; bi++; }
        const int bj = bi + rem;
        const int rowStart = bi * 128, colStart = bj * 128;

        f32x4 acc[4][4] = {};
        for (int k0 = 0; k0 < C_; k0 += 64) {
#pragma unroll
            for (int i = 0; i < 4; i++) {
                const int r8 = w * 32 + i * 8;
                dma16(xb + (size_t)(rowStart + r8 + ln8) * C_ + k0 + csw, &sm.stg.A[r8 * 64]);
                dma16(xb + (size_t)(colStart + r8 + ln8) * C_ + k0 + csw, &sm.stg.B[r8 * 64]);
            }
            __syncthreads();
#pragma unroll
            for (int ks = 0; ks < 2; ks++) {
                short8 af[4], bfr[4];
#pragma unroll
                for (int mt = 0; mt < 4; mt++) {
                    const int r = wr*64 + mt*16 + col16;
                    af[mt] = *(const short8*)&sm.stg.A[r * 64 + (((ks*4 + quad) ^ (r & 7)) * 8)];
                }
#pragma unroll
                for (int nt = 0; nt < 4; nt++) {
                    const int r = wc*64 + nt*16 + col16;
                    bfr[nt] = *(const short8*)&sm.stg.B[r * 64 + (((ks*4 + quad) ^ (r & 7)) * 8)];
                }
#pragma unroll
                for (int mt = 0; mt < 4; mt++)
#pragma unroll
                    for (int nt = 0; nt < 4; nt++)
                        acc[mt][nt] = __builtin_amdgcn_mfma_f32_16x16x32_bf16(
                            af[mt], bfr[nt], acc[mt][nt], 0, 0, 0);
            }
            __syncthreads();
        }

        // ---- epilogue: two 128x64 half-tiles, values stored as u16 KEYS ----
        for (int p = 0; p < 2; p++) {
            if (wc == p) {
#pragma unroll
                for (int mt = 0; mt < 4; mt++)
#pragma unroll
                    for (int nt = 0; nt < 4; nt++)
#pragma unroll
                        for (int r = 0; r < 4; r++)
                            sm.stile[(wr*64 + mt*16 + quad*4 + r) * 66 + nt*16 + col16] =
                                (unsigned short)bfkey(f2bf(acc[mt][nt][r]));
            }
            __syncthreads();
            {
                const int rr = t >> 1, seg = t & 1;
#pragma unroll
                for (int k = 0; k < 4; k++) {
                    short8 pk = *(const short8*)&sm.stile[rr * 66 + seg*32 + k*8];
                    *(short8*)&si[(size_t)(rowStart + rr) * N_ + colStart + p*64 + seg*32 + k*8] = pk;
                }
            }
            if (bi != bj) {
                const int cc = t >> 2, h2 = t & 3;
#pragma unroll
                for (int k = 0; k < 4; k++) {
                    short8 pk;
#pragma unroll
                    for (int e = 0; e < 8; e++)
                        pk[e] = (short)sm.stile[(h2*32 + k*8 + e) * 66 + cc];
                    *(short8*)&si[(size_t)(colStart + p*64 + cc) * N_ + rowStart + h2*32 + k*8] = pk;
                }
            }
            __syncthreads();
        }
    } else {
        // ========== u|v GEMM 128x64 tile, A = xh only (2-term split) ==========
        const int gb = blockIdx.x - NSYRK;          // 0..511
        const int rowStart = (gb >> 4) * 128;       // 32 row-tiles
        const int colStart = (gb & 15) * 64;        // 16 col-tiles (0..1023)

        f32x4 acc[4][2] = {};
        for (int k0 = 0; k0 < C_; k0 += 64) {
#pragma unroll
            for (int j = 0; j < 8; j++) {
                const int u = w * 8 + j;
                const unsigned short* gs; unsigned short* ld;
                if (u < 16)      { const int rb = u*8;       gs = xh + (size_t)(rowStart + rb + ln8) * C_; ld = sm.gm.Ah + rb*64; }
                else if (u < 24) { const int rb = (u-16)*8;  gs = wh + (size_t)(colStart + rb + ln8) * C_; ld = sm.gm.Bh + rb*64; }
                else             { const int rb = (u-24)*8;  gs = wl + (size_t)(colStart + rb + ln8) * C_; ld = sm.gm.Bl + rb*64; }
                dma16(gs + k0 + csw, ld);
            }
            __syncthreads();

#pragma unroll
            for (int ks = 0; ks < 2; ks++) {
                short8 bh2[2], bl2[2];
#pragma unroll
                for (int nt = 0; nt < 2; nt++) {
                    const int r = wc*32 + nt*16 + col16;
                    const int ro = r * 64 + (((ks*4 + quad) ^ (r & 7)) * 8);
                    bh2[nt] = *(const short8*)&sm.gm.Bh[ro];
                    bl2[nt] = *(const short8*)&sm.gm.Bl[ro];
                }
#pragma unroll
                for (int mt = 0; mt < 4; mt++) {
                    const int r = wr*64 + mt*16 + col16;
                    const int ro = r * 64 + (((ks*4 + quad) ^ (r & 7)) * 8);
                    short8 ah = *(const short8*)&sm.gm.Ah[ro];
#pragma unroll
                    for (int nt = 0; nt < 2; nt++) {
                        acc[mt][nt] = __builtin_amdgcn_mfma_f32_16x16x32_bf16(ah, bl2[nt], acc[mt][nt], 0, 0, 0);
                        acc[mt][nt] = __builtin_amdgcn_mfma_f32_16x16x32_bf16(ah, bh2[nt], acc[mt][nt], 0, 0, 0);
                    }
                }
            }
            __syncthreads();
        }

        if (colStart < 512) {   // u-part -> fp32 zu[N][512]
#pragma unroll
            for (int nt = 0; nt < 2; nt++) {
                const int col = colStart + wc*32 + nt*16 + col16;
                const float bns = Ub[col];
#pragma unroll
                for (int mt = 0; mt < 4; mt++)
#pragma unroll
                    for (int r = 0; r < 4; r++) {
                        const int row = rowStart + wr*64 + mt*16 + quad*4 + r;
                        zu[(size_t)row * 512 + col] = acc[mt][nt][r] + bns;
                    }
            }
        } else {                // v-part -> bf16 vb[N][512] (aggregate-only)
#pragma unroll
            for (int nt = 0; nt < 2; nt++) {
                const int col = colStart - 512 + wc*32 + nt*16 + col16;
                const float bns = Vb[col];
#pragma unroll
                for (int mt = 0; mt < 4; mt++)
#pragma unroll
                    for (int r = 0; r < 4; r++) {
                        const int row = rowStart + wr*64 + mt*16 + quad*4 + r;
                        vb[(size_t)row * 512 + col] = f2bf(acc[mt][nt][r] + bns);
                    }
            }
        }
    }
}

// ---------------------------------------------------------------------------
// Row selection + exact re-check, one wave per row (4 rows/block). si holds
// pre-transformed sortable keys; pack key<<16 | idx and compare as u32.
// ---------------------------------------------------------------------------
__global__ __launch_bounds__(256) void rowsel(
    const unsigned short* __restrict__ si, const float* __restrict__ x,
    int* __restrict__ nbr_idx, int* __restrict__ nbr_cnt,
    float* __restrict__ dinv_arr)
{
    const int wv = threadIdx.x >> 6, lane = threadIdx.x & 63;
    const int row = blockIdx.x * 4 + wv;

    u32 s[8] = {0, 0, 0, 0, 0, 0, 0, 0};
    const unsigned short* sr = si + (size_t)row * N_;
#pragma unroll
    for (int it = 0; it < 8; it++) {
        short8 pack = *(const short8*)&sr[it * 512 + lane * 8];
#pragma unroll
        for (int e = 0; e < 8; e++) {
            u32 key = ((u32)(unsigned short)pack[e] << 16) | (u32)(it * 512 + lane * 8 + e);
            key8_insert(s, key);
        }
    }
#pragma unroll
    for (int off = 1; off < 64; off <<= 1) {
        u32 o[8];
#pragma unroll
        for (int m = 0; m < 8; m++) o[m] = __shfl_xor(s[m], off);
#pragma unroll
        for (int m = 0; m < 8; m++) key8_insert(s, o[m]);
    }
    int tj[NCHK];
#pragma unroll
    for (int c = 0; c < NCHK; c++) tj[c] = (int)(s[c] & 0xFFFu);   // all lanes agree

    const float* xr = x + (size_t)row * C_;
    float xrv[8];
#pragma unroll
    for (int k = 0; k < 8; k++) xrv[k] = xr[lane + k*64];
    double dvr[NCHK];
#pragma unroll
    for (int c = 0; c < NCHK; c++) {
        const float* xj = x + (size_t)tj[c] * C_;
        double sum = 0.0;
#pragma unroll
        for (int k = 0; k < 8; k++)
            sum += (double)xrv[k] * (double)xj[lane + k*64];
#pragma unroll
        for (int off = 32; off; off >>= 1) sum += __shfl_xor(sum, off);
        dvr[c] = sum;
    }
    double m0 = -1e300, m1 = -1e300, m2 = -1e300, m3 = -1e300;
#pragma unroll
    for (int c = 0; c < NCHK; c++) {
        double v = dvr[c];
        if (v > m3) {
            if (v > m0)      { m3 = m2; m2 = m1; m1 = m0; m0 = v; }
            else if (v > m1) { m3 = m2; m2 = m1; m1 = v; }
            else if (v > m2) { m3 = m2; m2 = v; }
            else               m3 = v;
        }
    }
    const double thr = m3;
    if (lane == 0) {
        int cnt = 0;
#pragma unroll
        for (int c = 0; c < NCHK; c++) {
            bool keep = dvr[c] >= thr;
            if (keep) nbr_idx[(size_t)row * MAXN + cnt] = tj[c];
            cnt += keep ? 1 : 0;
        }
        nbr_cnt[row]  = cnt;
        dinv_arr[row] = (float)(1.0 / sqrt((double)cnt));
    }
}

// ---------------------------------------------------------------------------
// One wave per row (1024 blocks -> full latency-hiding TLP): z = u(fp32) +
// di*sum_j w_j v_j(bf16 gather) ; BN over C ; h = relu(x+norm) -> bf16 hi/lo.
// [R13 lesson: do NOT fuse this with fc — the gather needs wave count.]
// ---------------------------------------------------------------------------
__global__ __launch_bounds__(256) void aggregate_bn(
    const float* __restrict__ x, const float* __restrict__ zu,
    const unsigned short* __restrict__ vb,
    const int* __restrict__ nbr_idx, const int* __restrict__ nbr_cnt,
    const float* __restrict__ dinv_arr,
    unsigned short* __restrict__ hh, unsigned short* __restrict__ hl)
{
    const int wv = threadIdx.x >> 6, lane = threadIdx.x & 63;
    const int row = blockIdx.x * 4 + wv;
    const int cnt = nbr_cnt[row];
    const float di = dinv_arr[row];
    const int c0 = lane * 8;

    const float* zr = zu + (size_t)row * 512 + c0;
    float4 z0 = *(const float4*)zr;
    float4 z1 = *(const float4*)(zr + 4);
#pragma unroll
    for (int m = 0; m < MAXN; m++) {
        if (m < cnt) {
            const int j = nbr_idx[(size_t)row * MAXN + m];
            const float wgt = di * dinv_arr[j];
            short8 vv = *(const short8*)&vb[(size_t)j * 512 + c0];
            z0.x += wgt * bf2f((unsigned short)vv[0]);
            z0.y += wgt * bf2f((unsigned short)vv[1]);
            z0.z += wgt * bf2f((unsigned short)vv[2]);
            z0.w += wgt * bf2f((unsigned short)vv[3]);
            z1.x += wgt * bf2f((unsigned short)vv[4]);
            z1.y += wgt * bf2f((unsigned short)vv[5]);
            z1.z += wgt * bf2f((unsigned short)vv[6]);
            z1.w += wgt * bf2f((unsigned short)vv[7]);
        }
    }
    float sum  = z0.x + z0.y + z0.z + z0.w + z1.x + z1.y + z1.z + z1.w;
    float sumq = z0.x*z0.x + z0.y*z0.y + z0.z*z0.z + z0.w*z0.w
               + z1.x*z1.x + z1.y*z1.y + z1.z*z1.z + z1.w*z1.w;
#pragma unroll
    for (int off = 32; off; off >>= 1) {
        sum  += __shfl_xor(sum, off);
        sumq += __shfl_xor(sumq, off);
    }
    const float mean = sum / (float)C_;
    const float var  = sumq / (float)C_ - mean * mean;
    const float istd = 1.0f / sqrtf(var + EPSF);

    const float* xr = x + (size_t)row * C_ + c0;
    float4 x0 = *(const float4*)xr;
    float4 x1 = *(const float4*)(xr + 4);
    float hv[8];
    hv[0] = fmaxf(x0.x + (z0.x - mean) * istd, 0.f);
    hv[1] = fmaxf(x0.y + (z0.y - mean) * istd, 0.f);
    hv[2] = fmaxf(x0.z + (z0.z - mean) * istd, 0.f);
    hv[3] = fmaxf(x0.w + (z0.w - mean) * istd, 0.f);
    hv[4] = fmaxf(x1.x + (z1.x - mean) * istd, 0.f);
    hv[5] = fmaxf(x1.y + (z1.y - mean) * istd, 0.f);
    hv[6] = fmaxf(x1.z + (z1.z - mean) * istd, 0.f);
    hv[7] = fmaxf(x1.w + (z1.w - mean) * istd, 0.f);
    short8 hb, lb;
#pragma unroll
    for (int e = 0; e < 8; e++) {
        unsigned short b = f2bf(hv[e]);
        hb[e] = (short)b;
        lb[e] = (short)f2bf(hv[e] - bf2f(b));
    }
    *(short8*)&hh[(size_t)row * C_ + c0] = hb;
    *(short8*)&hl[(size_t)row * C_ + c0] = lb;
}

// ---------------------------------------------------------------------------
// fc GEMM, 64x64 tiles (grid 4x64 = 256 blocks -> full CU coverage).
// 3-term split-bf16: (hh+hl)@(fh+fl)^T + fc_b. Wave w stages plane w.
// ---------------------------------------------------------------------------
__global__ __launch_bounds__(256) void gemm_fc64(
    const unsigned short* __restrict__ Ah, const unsigned short* __restrict__ Al,
    const unsigned short* __restrict__ Bh, const unsigned short* __restrict__ Bl,
    const float* __restrict__ bias, float* __restrict__ out)
{
    __shared__ unsigned short P[4 * 64 * 64];   // planes Ah|Al|Bh|Bl, 32 KB
    const int t = threadIdx.x;
    const int lane = t & 63, w = t >> 6;
    const int wr = w >> 1, wc = w & 1;
    const int col16 = lane & 15, quad = lane >> 4;
    const int ln8 = lane >> 3;
    const int csw = ((lane & 7) ^ ln8) * 8;
    const int rowStart = blockIdx.y * 64, colStart = blockIdx.x * 64;

    const unsigned short* gsel = (w == 0) ? Ah : (w == 1) ? Al : (w == 2) ? Bh : Bl;
    const int gRow = (w < 2) ? rowStart : colStart;
    unsigned short* lbase = P + w * 4096;

    f32x4 acc[2][2] = {};
    for (int k0 = 0; k0 < C_; k0 += 64) {
#pragma unroll
        for (int j = 0; j < 8; j++)
            dma16(gsel + (size_t)(gRow + j*8 + ln8) * C_ + k0 + csw, lbase + j*8*64);
        __syncthreads();
#pragma unroll
        for (int ks = 0; ks < 2; ks++) {
            short8 ah[2], al[2], bh[2], bl[2];
#pragma unroll
            for (int mt = 0; mt < 2; mt++) {
                const int r = wr*32 + mt*16 + col16;
                const int ro = r * 64 + (((ks*4 + quad) ^ (r & 7)) * 8);
                ah[mt] = *(const short8*)&P[0*4096 + ro];
                al[mt] = *(const short8*)&P[1*4096 + ro];
            }
#pragma unroll
            for (int nt = 0; nt < 2; nt++) {
                const int r = wc*32 + nt*16 + col16;
                const int ro = r * 64 + (((ks*4 + quad) ^ (r & 7)) * 8);
                bh[nt] = *(const short8*)&P[2*4096 + ro];
                bl[nt] = *(const short8*)&P[3*4096 + ro];
            }
#pragma unroll
            for (int mt = 0; mt < 2; mt++)
#pragma unroll
                for (int nt = 0; nt < 2; nt++) {
                    acc[mt][nt] = __builtin_amdgcn_mfma_f32_16x16x32_bf16(al[mt], bh[nt], acc[mt][nt], 0, 0, 0);
                    acc[mt][nt] = __builtin_amdgcn_mfma_f32_16x16x32_bf16(ah[mt], bl[nt], acc[mt][nt], 0, 0, 0);
                    acc[mt][nt] = __builtin_amdgcn_mfma_f32_16x16x32_bf16(ah[mt], bh[nt], acc[mt][nt], 0, 0, 0);
                }
        }
        __syncthreads();
    }

#pragma unroll
    for (int nt = 0; nt < 2; nt++) {
        const int col = colStart + wc*32 + nt*16 + col16;
        const float bns = bias[col];
#pragma unroll
        for (int mt = 0; mt < 2; mt++)
#pragma unroll
            for (int r = 0; r < 4; r++) {
                const int row = rowStart + wr*32 + mt*16 + quad*4 + r;
                out[(size_t)row * OUT_ + col] = acc[mt][nt][r] + bns;
            }
    }
}

// ---------------------------------------------------------------------------
extern "C" void kernel_launch(void* const* d_in, const int* in_sizes, int n_in,
                              void* d_out, int out_size, void* d_ws, size_t ws_size,
                              hipStream_t stream)
{
    const float* x    = (const float*)d_in[0];
    const float* U_w  = (const float*)d_in[1];
    const float* U_b  = (const float*)d_in[2];
    const float* V_w  = (const float*)d_in[3];
    const float* V_b  = (const float*)d_in[4];
    const float* fc_w = (const float*)d_in[5];
    const float* fc_b = (const float*)d_in[6];
    float* out = (float*)d_out;

    char* p = (char*)d_ws;
    auto alloc = [&](size_t bytes) { char* r = p; p += (bytes + 255) & ~(size_t)255; return r; };
    unsigned short* si = (unsigned short*)alloc((size_t)N_ * N_ * 2);     // 32 MB (keys)
    unsigned short* xh = (unsigned short*)alloc((size_t)N_ * C_ * 2);
    unsigned short* wh = (unsigned short*)alloc((size_t)1024 * C_ * 2);   // [U_w; V_w] hi
    unsigned short* wl = (unsigned short*)alloc((size_t)1024 * C_ * 2);   // [U_w; V_w] lo
    unsigned short* fh = (unsigned short*)alloc((size_t)OUT_ * C_ * 2);
    unsigned short* fl = (unsigned short*)alloc((size_t)OUT_ * C_ * 2);
    unsigned short* hh = (unsigned short*)alloc((size_t)N_ * C_ * 2);
    unsigned short* hl = (unsigned short*)alloc((size_t)N_ * C_ * 2);
    float*          zu = (float*)alloc((size_t)N_ * 512 * 4);             // u fp32
    unsigned short* vb = (unsigned short*)alloc((size_t)N_ * 512 * 2);    // v bf16
    int*   nbr_idx  = (int*)  alloc((size_t)N_ * MAXN * 4);
    int*   nbr_cnt  = (int*)  alloc((size_t)N_ * 4);
    float* dinv     = (float*)alloc((size_t)N_ * 4);

    // 1. fp32 -> bf16 planes (x hi-only; U/V and fc hi+lo)
    hipLaunchKernelGGL(split_all, dim3(TOTF4 / 256), dim3(256), 0, stream,
                       x, U_w, V_w, fc_w, xh, wh, wl, fh, fl);

    // 2. fused: triangle similarity (key-encoded, mirrored) + [u|v] GEMM
    hipLaunchKernelGGL(simuv, dim3(NSYRK + NUV), dim3(256), 0, stream,
                       xh, si, xh, wh, wl, U_b, V_b, zu, vb);

    // 3. per-row packed-key top-8 + fp64 re-check -> neighbors, deg, dinv
    hipLaunchKernelGGL(rowsel, dim3(N_/4), dim3(256), 0, stream,
                       si, x, nbr_idx, nbr_cnt, dinv);

    // 4. aggregate + BN + relu -> h (bf16 split) — 1024 blocks for gather TLP
    hipLaunchKernelGGL(aggregate_bn, dim3(N_/4), dim3(256), 0, stream,
                       x, zu, vb, nbr_idx, nbr_cnt, dinv, hh, hl);

    // 5. out = h @ fc_w.T + fc_b  (256 blocks)
    hipLaunchKernelGGL(gemm_fc64, dim3(OUT_/64, N_/64), dim3(256), 0, stream,
                       hh, hl, fh, fl, fc_b, out);
}